// Round 1
// baseline (96.118 us; speedup 1.0000x reference)
//
#include <hip/hip_runtime.h>
#include <hip/hip_bf16.h>

// LatticeSnake: B=32, L=512, W=9. One block per (b,i) window.
// Each window region of 729 fp32 cells is exclusively owned by its block:
// stage in LDS, scatter-add snake points, write the full tile (no memset needed).

constexpr int L  = 512;
constexpr int W  = 9;
constexpr int W3 = W * W * W;      // 729
constexpr int HALF = W / 2;        // 4
constexpr int M  = 2 * L - 1;      // 1023 snake points (residues + midpoints)

__global__ __launch_bounds__(256) void lattice_snake_kernel(
    const float* __restrict__ acids,   // [B, L]
    const float* __restrict__ mask,    // [B, L]
    const int*   __restrict__ idx,     // [B, L, 3]
    float*       __restrict__ out)     // [B, L, W,W,W,1]
{
    const int bi = blockIdx.x;         // b*L + i
    const int b  = bi >> 9;            // / 512
    const int i  = bi & (L - 1);

    __shared__ float win[W3];
    for (int k = threadIdx.x; k < W3; k += blockDim.x) win[k] = 0.0f;
    __syncthreads();

    const int*   idxb = idx   + (size_t)b * L * 3;
    const float* ab   = acids + (size_t)b * L;
    const float* mb   = mask  + (size_t)b * L;

    // Window center in doubled coords: 2*(idx + (L-1)).
    const int cx = 2 * idxb[3 * i + 0] + 2 * (L - 1);
    const int cy = 2 * idxb[3 * i + 1] + 2 * (L - 1);
    const int cz = 2 * idxb[3 * i + 2] + 2 * (L - 1);

    for (int m = threadIdx.x; m < M; m += blockDim.x) {
        int px, py, pz;
        float v;
        if (m < L) {
            // Residue point: doubled coord = 2*idx + 2*(L-1), value = acids*mask.
            px = 2 * idxb[3 * m + 0] + 2 * (L - 1);
            py = 2 * idxb[3 * m + 1] + 2 * (L - 1);
            pz = 2 * idxb[3 * m + 2] + 2 * (L - 1);
            v  = ab[m] * mb[m];
        } else {
            // Bond midpoint j..j+1: (idx2[j]+idx2[j+1])/2 = idx[j]+idx[j+1]+2*(L-1).
            const int j = m - L;
            px = idxb[3 * j + 0] + idxb[3 * j + 3] + 2 * (L - 1);
            py = idxb[3 * j + 1] + idxb[3 * j + 4] + 2 * (L - 1);
            pz = idxb[3 * j + 2] + idxb[3 * j + 5] + 2 * (L - 1);
            v  = (ab[j] + ab[j + 1] + 1.0f) * mb[j + 1];
        }
        const int rx = px - cx + HALF;
        const int ry = py - cy + HALF;
        const int rz = pz - cz + HALF;
        if ((unsigned)rx < (unsigned)W && (unsigned)ry < (unsigned)W &&
            (unsigned)rz < (unsigned)W) {
            atomicAdd(&win[(rx * W + ry) * W + rz], v);
        }
    }
    __syncthreads();

    float* ob = out + (size_t)bi * W3;
    for (int k = threadIdx.x; k < W3; k += blockDim.x) ob[k] = win[k];
}

extern "C" void kernel_launch(void* const* d_in, const int* in_sizes, int n_in,
                              void* d_out, int out_size, void* d_ws, size_t ws_size,
                              hipStream_t stream) {
    const float* acids = (const float*)d_in[0];
    const float* mask  = (const float*)d_in[1];
    const int*   idx   = (const int*)d_in[2];
    float*       out   = (float*)d_out;

    const int B = in_sizes[0] / L;           // 32
    const int nblocks = B * L;               // 16384 windows

    lattice_snake_kernel<<<nblocks, 256, 0, stream>>>(acids, mask, idx, out);
}

// Round 2
// 88.267 us; speedup vs baseline: 1.0889x; 1.0889x over previous
//
#include <hip/hip_runtime.h>
#include <hip/hip_bf16.h>

// LatticeSnake: B=32, L=512, W=9.
// One block per group of G=8 consecutive windows of one batch. Consecutive
// window centers differ by <=2 (doubled coords), so the union of 8 windows
// fits in a <=23^3 box. Scatter all M=1023 snake points once into the actual
// bounding box in LDS, then emit each window's 9^3 tile from the box.

constexpr int L    = 512;
constexpr int W    = 9;
constexpr int W3   = W * W * W;        // 729
constexpr int HALF = W / 2;            // 4
constexpr int M    = 2 * L - 1;        // 1023 snake points
constexpr int G    = 8;                // windows per block
constexpr int BOXW = 2 * (G - 1) + W;  // 23 (worst-case box width)
constexpr int BOXN = BOXW * BOXW * BOXW; // 12167 floats = 48.7 KB

__global__ __launch_bounds__(256) void lattice_snake_kernel(
    const float* __restrict__ acids,   // [B, L]
    const float* __restrict__ mask,    // [B, L]
    const int*   __restrict__ idx,     // [B, L, 3]
    float*       __restrict__ out)     // [B, L, 9,9,9,1]
{
    const int blk = blockIdx.x;
    const int b   = blk >> 6;          // / (L/G) = 64 groups per batch
    const int g   = blk & 63;
    const int i0  = g * G;
    const int tid = threadIdx.x;

    const int*   idxb = idx   + (size_t)b * L * 3;
    const float* ab   = acids + (size_t)b * L;
    const float* mb   = mask  + (size_t)b * L;

    // --- centers of the 8 windows (doubled coords) + actual bounding box ---
    int cxs[G], cys[G], czs[G];
    int mnx =  1 << 30, mny =  1 << 30, mnz =  1 << 30;
    int mxx = -(1 << 30), mxy = -(1 << 30), mxz = -(1 << 30);
#pragma unroll
    for (int w = 0; w < G; ++w) {
        const int ii = i0 + w;
        const int cx = 2 * idxb[3 * ii + 0] + 2 * (L - 1);
        const int cy = 2 * idxb[3 * ii + 1] + 2 * (L - 1);
        const int cz = 2 * idxb[3 * ii + 2] + 2 * (L - 1);
        cxs[w] = cx; cys[w] = cy; czs[w] = cz;
        mnx = min(mnx, cx); mxx = max(mxx, cx);
        mny = min(mny, cy); mxy = max(mxy, cy);
        mnz = min(mnz, cz); mxz = max(mxz, cz);
    }
    const int ox = mnx - HALF, oy = mny - HALF, oz = mnz - HALF;
    const int dxd = mxx - mnx + W;     // actual box dims, each <= 23
    const int dyd = mxy - mny + W;
    const int dzd = mxz - mnz + W;
    const int nbox = dxd * dyd * dzd;

    __shared__ float box[BOXN];
    for (int k = tid; k < nbox; k += 256) box[k] = 0.0f;
    __syncthreads();

    // --- scatter all snake points that land in the box ---
    for (int m = tid; m < M; m += 256) {
        int px, py, pz;
        float v;
        if (m < L) {
            px = 2 * idxb[3 * m + 0] + 2 * (L - 1);
            py = 2 * idxb[3 * m + 1] + 2 * (L - 1);
            pz = 2 * idxb[3 * m + 2] + 2 * (L - 1);
            v  = ab[m] * mb[m];
        } else {
            const int j = m - L;       // midpoint between residues j, j+1
            px = idxb[3 * j + 0] + idxb[3 * j + 3] + 2 * (L - 1);
            py = idxb[3 * j + 1] + idxb[3 * j + 4] + 2 * (L - 1);
            pz = idxb[3 * j + 2] + idxb[3 * j + 5] + 2 * (L - 1);
            v  = (ab[j] + ab[j + 1] + 1.0f) * mb[j + 1];
        }
        const int rx = px - ox, ry = py - oy, rz = pz - oz;
        if ((unsigned)rx < (unsigned)dxd && (unsigned)ry < (unsigned)dyd &&
            (unsigned)rz < (unsigned)dzd) {
            atomicAdd(&box[(rx * dyd + ry) * dzd + rz], v);
        }
    }
    __syncthreads();

    // --- emit the 8 windows from the box ---
    float* ob = out + ((size_t)b * L + i0) * W3;
#pragma unroll
    for (int w = 0; w < G; ++w) {
        const int bx = cxs[w] - HALF - ox;
        const int by = cys[w] - HALF - oy;
        const int bz = czs[w] - HALF - oz;
        for (int k = tid; k < W3; k += 256) {
            const int dx = k / 81;
            const int r  = k - dx * 81;
            const int dy = r / 9;
            const int dz = r - dy * 9;
            const float val =
                box[((bx + dx) * dyd + (by + dy)) * dzd + (bz + dz)];
            __builtin_nontemporal_store(val, &ob[(size_t)w * W3 + k]);
        }
    }
}

extern "C" void kernel_launch(void* const* d_in, const int* in_sizes, int n_in,
                              void* d_out, int out_size, void* d_ws, size_t ws_size,
                              hipStream_t stream) {
    const float* acids = (const float*)d_in[0];
    const float* mask  = (const float*)d_in[1];
    const int*   idx   = (const int*)d_in[2];
    float*       out   = (float*)d_out;

    const int B = in_sizes[0] / L;            // 32
    const int nblocks = B * (L / G);          // 2048 window groups

    lattice_snake_kernel<<<nblocks, 256, 0, stream>>>(acids, mask, idx, out);
}

// Round 4
// 86.976 us; speedup vs baseline: 1.1051x; 1.0148x over previous
//
#include <hip/hip_runtime.h>
#include <hip/hip_bf16.h>

// LatticeSnake: B=32, L=512, W=9.
// One block per group of G=8 consecutive windows of one batch. Consecutive
// window centers differ by <=2 (doubled coords), so the union of 8 windows
// fits in a <=23^3 box. Scatter all M=1023 snake points once into the actual
// bounding box in LDS, then emit all 8 windows' tiles as one flat
// float4-vectorized stream (block output base is 32B-aligned: i0 % 8 == 0).

constexpr int L    = 512;
constexpr int W    = 9;
constexpr int W3   = W * W * W;          // 729
constexpr int HALF = W / 2;              // 4
constexpr int M    = 2 * L - 1;          // 1023 snake points
constexpr int G    = 8;                  // windows per block
constexpr int BOXW = 2 * (G - 1) + W;    // 23 (worst-case box width)
constexpr int BOXN = BOXW * BOXW * BOXW; // 12167 floats = 48.7 KB

typedef float vfloat4 __attribute__((ext_vector_type(4)));

__global__ __launch_bounds__(256) void lattice_snake_kernel(
    const float* __restrict__ acids,   // [B, L]
    const float* __restrict__ mask,    // [B, L]
    const int*   __restrict__ idx,     // [B, L, 3]
    float*       __restrict__ out)     // [B, L, 9,9,9,1]
{
    const int blk = blockIdx.x;
    const int b   = blk >> 6;          // / (L/G) = 64 groups per batch
    const int g   = blk & 63;
    const int i0  = g * G;
    const int tid = threadIdx.x;

    const int*   idxb = idx   + (size_t)b * L * 3;
    const float* ab   = acids + (size_t)b * L;
    const float* mb   = mask  + (size_t)b * L;

    // --- centers of the 8 windows (doubled coords) + actual bounding box ---
    int cxs[G], cys[G], czs[G];
    int mnx =  1 << 30, mny =  1 << 30, mnz =  1 << 30;
    int mxx = -(1 << 30), mxy = -(1 << 30), mxz = -(1 << 30);
#pragma unroll
    for (int w = 0; w < G; ++w) {
        const int ii = i0 + w;
        const int cx = 2 * idxb[3 * ii + 0] + 2 * (L - 1);
        const int cy = 2 * idxb[3 * ii + 1] + 2 * (L - 1);
        const int cz = 2 * idxb[3 * ii + 2] + 2 * (L - 1);
        cxs[w] = cx; cys[w] = cy; czs[w] = cz;
        mnx = min(mnx, cx); mxx = max(mxx, cx);
        mny = min(mny, cy); mxy = max(mxy, cy);
        mnz = min(mnz, cz); mxz = max(mxz, cz);
    }
    const int ox = mnx - HALF, oy = mny - HALF, oz = mnz - HALF;
    const int dxd = mxx - mnx + W;     // actual box dims, each <= 23
    const int dyd = mxy - mny + W;
    const int dzd = mxz - mnz + W;
    const int nbox  = dxd * dyd * dzd;
    const int dydzd = dyd * dzd;

    __shared__ float box[BOXN];
    __shared__ int   win_base[G];      // per-window base linear offset in box

    for (int k = tid; k < nbox; k += 256) box[k] = 0.0f;
    if (tid == 0) {
#pragma unroll
        for (int w = 0; w < G; ++w) {
            const int bx = cxs[w] - HALF - ox;
            const int by = cys[w] - HALF - oy;
            const int bz = czs[w] - HALF - oz;
            win_base[w] = bx * dydzd + by * dzd + bz;
        }
    }
    __syncthreads();

    // --- scatter all snake points that land in the box ---
    for (int m = tid; m < M; m += 256) {
        int px, py, pz;
        float v;
        if (m < L) {
            px = 2 * idxb[3 * m + 0] + 2 * (L - 1);
            py = 2 * idxb[3 * m + 1] + 2 * (L - 1);
            pz = 2 * idxb[3 * m + 2] + 2 * (L - 1);
            v  = ab[m] * mb[m];
        } else {
            const int j = m - L;       // midpoint between residues j, j+1
            px = idxb[3 * j + 0] + idxb[3 * j + 3] + 2 * (L - 1);
            py = idxb[3 * j + 1] + idxb[3 * j + 4] + 2 * (L - 1);
            pz = idxb[3 * j + 2] + idxb[3 * j + 5] + 2 * (L - 1);
            v  = (ab[j] + ab[j + 1] + 1.0f) * mb[j + 1];
        }
        const int rx = px - ox, ry = py - oy, rz = pz - oz;
        if ((unsigned)rx < (unsigned)dxd && (unsigned)ry < (unsigned)dyd &&
            (unsigned)rz < (unsigned)dzd) {
            atomicAdd(&box[(rx * dyd + ry) * dzd + rz], v);
        }
    }
    __syncthreads();

    // --- emit: 8 windows = 5832 contiguous floats, float4 stores ---
    // Block base element index = (b*512 + i0)*729 with i0 % 8 == 0
    // -> multiple of 8 elements -> 32B aligned.
    float* ob = out + ((size_t)b * L + i0) * W3;
    for (int e = tid * 4; e < G * W3; e += 256 * 4) {
        vfloat4 v4;
#pragma unroll
        for (int u = 0; u < 4; ++u) {
            const int ee = e + u;
            const int w  = ee / W3;          // window in group (magic-mul)
            const int k  = ee - w * W3;
            const int dx = k / 81;
            const int r  = k - dx * 81;
            const int dy = r / 9;
            const int dz = r - dy * 9;
            v4[u] = box[win_base[w] + dx * dydzd + dy * dzd + dz];
        }
        __builtin_nontemporal_store(v4, (vfloat4*)(ob + e));
    }
}

extern "C" void kernel_launch(void* const* d_in, const int* in_sizes, int n_in,
                              void* d_out, int out_size, void* d_ws, size_t ws_size,
                              hipStream_t stream) {
    const float* acids = (const float*)d_in[0];
    const float* mask  = (const float*)d_in[1];
    const int*   idx   = (const int*)d_in[2];
    float*       out   = (float*)d_out;

    const int B = in_sizes[0] / L;            // 32
    const int nblocks = B * (L / G);          // 2048 window groups

    lattice_snake_kernel<<<nblocks, 256, 0, stream>>>(acids, mask, idx, out);
}